// Round 1
// baseline (564.419 us; speedup 1.0000x reference)
//
#include <hip/hip_runtime.h>
#include <hip/hip_bf16.h>
#include <math.h>

// Problem constants (match reference)
#define BATCH 32
#define SEQ   4096
#define HID   768
#define CHR   32
#define NSEG  2048
#define TTOK  16384
#define KF    (HID + CHR)   // 800
#define D1    512
#define D2    512

// ---------------------------------------------------------------------------
// Kernel 1: segment-mean pooling + concat(base_characteristics)
// One block per segment (segment_ids sorted ascending). Binary-search the
// token range, sum gathered rows, mean, write feats[n][0:800].
// ---------------------------------------------------------------------------
__global__ __launch_bounds__(256) void pool_kernel(
    const float* __restrict__ hs,      // [B*S, H]
    const float* __restrict__ basec,   // [N, C]
    const int*   __restrict__ tok,     // [T]
    const int*   __restrict__ seg,     // [T], sorted
    float*       __restrict__ feats)   // [N, KF]
{
    const int n   = blockIdx.x;
    const int tid = threadIdx.x;

    // lower_bound(seg, n)
    int lo;
    {
        int l = 0, r = TTOK;
        while (l < r) { int m = (l + r) >> 1; if (seg[m] < n) l = m + 1; else r = m; }
        lo = l;
    }
    // lower_bound(seg, n+1)
    int hi;
    {
        int l = lo, r = TTOK;
        while (l < r) { int m = (l + r) >> 1; if (seg[m] < n + 1) l = m + 1; else r = m; }
        hi = l;
    }

    float a0 = 0.f, a1 = 0.f, a2 = 0.f;
    for (int t = lo; t < hi; ++t) {
        const float* row = hs + (long)tok[t] * HID;
        a0 += row[tid];
        a1 += row[tid + 256];
        a2 += row[tid + 512];
    }
    const float inv = 1.0f / (float)((hi - lo) > 0 ? (hi - lo) : 1);
    float* frow = feats + (long)n * KF;
    frow[tid]       = a0 * inv;
    frow[tid + 256] = a1 * inv;
    frow[tid + 512] = a2 * inv;
    if (tid < CHR) frow[HID + tid] = basec[n * CHR + tid];
}

// ---------------------------------------------------------------------------
// Kernel 2/3: fp32 tiled GEMM + bias + ReLU.  C[M,N] = relu(A[M,K]@B[K,N]+bias)
// 64x64 block tile, BK=16, 256 threads, 4x4 micro-tile per thread.
// Requires M%64==0, N%64==0, K%BK==0 (true for all our shapes).
// ---------------------------------------------------------------------------
template <int BK>
__global__ __launch_bounds__(256) void gemm_bias_relu(
    const float* __restrict__ A,    // [M,K]
    const float* __restrict__ B,    // [K,N]
    const float* __restrict__ bias, // [N]
    float*       __restrict__ Cc,   // [M,N]
    int M, int N, int K)
{
    __shared__ float As[BK][68];   // A^T tile: As[k][m], pad 64->68 (16B-aligned)
    __shared__ float Bs[BK][68];   // B tile:   Bs[k][n]

    const int tid = threadIdx.x;
    const int bm  = blockIdx.x * 64;
    const int bn  = blockIdx.y * 64;
    const int tx  = tid & 15;   // column group: cols tx*4 .. tx*4+3
    const int ty  = tid >> 4;   // row group:    rows ty*4 .. ty*4+3

    float acc[4][4];
    #pragma unroll
    for (int i = 0; i < 4; ++i)
        #pragma unroll
        for (int j = 0; j < 4; ++j) acc[i][j] = 0.f;

    for (int k0 = 0; k0 < K; k0 += BK) {
        // Stage A tile (64 rows x BK cols), store transposed
        #pragma unroll
        for (int i = 0; i < (64 * BK) / 256; ++i) {
            int idx = tid + i * 256;
            int r = idx / BK, kk = idx % BK;
            As[kk][r] = A[(long)(bm + r) * K + (k0 + kk)];
        }
        // Stage B tile (BK rows x 64 cols)
        #pragma unroll
        for (int i = 0; i < (64 * BK) / 256; ++i) {
            int idx = tid + i * 256;
            int kk = idx / 64, c = idx % 64;
            Bs[kk][c] = B[(long)(k0 + kk) * N + (bn + c)];
        }
        __syncthreads();

        #pragma unroll
        for (int kk = 0; kk < BK; ++kk) {
            float a[4], b[4];
            #pragma unroll
            for (int i = 0; i < 4; ++i) a[i] = As[kk][ty * 4 + i];
            #pragma unroll
            for (int j = 0; j < 4; ++j) b[j] = Bs[kk][tx * 4 + j];
            #pragma unroll
            for (int i = 0; i < 4; ++i)
                #pragma unroll
                for (int j = 0; j < 4; ++j)
                    acc[i][j] = fmaf(a[i], b[j], acc[i][j]);
        }
        __syncthreads();
    }

    #pragma unroll
    for (int i = 0; i < 4; ++i) {
        int row = bm + ty * 4 + i;
        #pragma unroll
        for (int j = 0; j < 4; ++j) {
            int col = bn + tx * 4 + j;
            float v = acc[i][j] + bias[col];
            Cc[(long)row * N + col] = fmaxf(v, 0.0f);
        }
    }
}

// ---------------------------------------------------------------------------
// Kernel 4: score[n] = sigmoid(dot(h2[n,:], w3) + b3). One wave per row.
// ---------------------------------------------------------------------------
__global__ __launch_bounds__(256) void final_kernel(
    const float* __restrict__ h2,  // [N, D2]
    const float* __restrict__ w3,  // [D2]
    const float* __restrict__ b3,  // [1]
    float*       __restrict__ out) // [N]
{
    const int wave = threadIdx.x >> 6;
    const int lane = threadIdx.x & 63;
    const int n = blockIdx.x * 4 + wave;
    if (n >= NSEG) return;

    const float* row = h2 + (long)n * D2;
    float s = 0.f;
    #pragma unroll
    for (int i = 0; i < D2 / 64; ++i)
        s = fmaf(row[lane + i * 64], w3[lane + i * 64], s);

    #pragma unroll
    for (int off = 32; off > 0; off >>= 1)
        s += __shfl_xor(s, off, 64);

    if (lane == 0) {
        float x = s + b3[0];
        out[n] = 1.0f / (1.0f + expf(-x));
    }
}

// ---------------------------------------------------------------------------
extern "C" void kernel_launch(void* const* d_in, const int* in_sizes, int n_in,
                              void* d_out, int out_size, void* d_ws, size_t ws_size,
                              hipStream_t stream) {
    const float* hs    = (const float*)d_in[0];   // [B,S,H]
    const float* basec = (const float*)d_in[1];   // [N,C]
    const float* w1    = (const float*)d_in[2];   // [800,512]
    const float* b1    = (const float*)d_in[3];   // [512]
    const float* w2    = (const float*)d_in[4];   // [512,512]
    const float* b2    = (const float*)d_in[5];   // [512]
    const float* w3    = (const float*)d_in[6];   // [512,1]
    const float* b3    = (const float*)d_in[7];   // [1]
    const int*   tok   = (const int*)d_in[8];     // [T]
    const int*   seg   = (const int*)d_in[9];     // [T]
    float*       out   = (float*)d_out;           // [1,N] -> N floats

    float* feats = (float*)d_ws;                  // [N, 800]
    float* h1    = feats + (size_t)NSEG * KF;     // [N, 512]
    float* h2    = h1    + (size_t)NSEG * D1;     // [N, 512]

    pool_kernel<<<NSEG, 256, 0, stream>>>(hs, basec, tok, seg, feats);

    dim3 g1(NSEG / 64, D1 / 64);  // 32 x 8
    gemm_bias_relu<16><<<g1, 256, 0, stream>>>(feats, w1, b1, h1, NSEG, D1, KF);

    dim3 g2(NSEG / 64, D2 / 64);  // 32 x 8
    gemm_bias_relu<16><<<g2, 256, 0, stream>>>(h1, w2, b2, h2, NSEG, D2, D1);

    final_kernel<<<NSEG / 4, 256, 0, stream>>>(h2, w3, b3, out);
}

// Round 3
// 490.126 us; speedup vs baseline: 1.1516x; 1.1516x over previous
//
#include <hip/hip_runtime.h>
#include <hip/hip_bf16.h>
#include <math.h>

// Problem constants
#define HID   768
#define CHR   32
#define NSEG  2048
#define TTOK  16384
#define KF    800           // HID + CHR
#define D1    512
#define D2    512

typedef __hip_bfloat16 bf16;
typedef __attribute__((ext_vector_type(8))) short short8;   // 8 bf16 = 4 VGPR
typedef __attribute__((ext_vector_type(4))) float floatx4;

// ---------------------------------------------------------------------------
// Kernel 1: segment-mean pooling + concat(base_characteristics) -> bf16 feats
// One block per segment (segment_ids sorted). fp32 accumulate, bf16 store.
// ---------------------------------------------------------------------------
__global__ __launch_bounds__(256) void pool_kernel(
    const float* __restrict__ hs,      // [B*S, H]
    const float* __restrict__ basec,   // [N, C]
    const int*   __restrict__ tok,     // [T]
    const int*   __restrict__ seg,     // [T], sorted
    bf16*        __restrict__ feats)   // [N, KF] bf16
{
    const int n   = blockIdx.x;
    const int tid = threadIdx.x;

    int lo;
    {
        int l = 0, r = TTOK;
        while (l < r) { int m = (l + r) >> 1; if (seg[m] < n) l = m + 1; else r = m; }
        lo = l;
    }
    int hi;
    {
        int l = lo, r = TTOK;
        while (l < r) { int m = (l + r) >> 1; if (seg[m] < n + 1) l = m + 1; else r = m; }
        hi = l;
    }

    float a0 = 0.f, a1 = 0.f, a2 = 0.f;
    for (int t = lo; t < hi; ++t) {
        const float* row = hs + (long)tok[t] * HID;
        a0 += row[tid];
        a1 += row[tid + 256];
        a2 += row[tid + 512];
    }
    const float inv = 1.0f / (float)((hi - lo) > 0 ? (hi - lo) : 1);
    bf16* frow = feats + (long)n * KF;
    frow[tid]       = __float2bfloat16(a0 * inv);
    frow[tid + 256] = __float2bfloat16(a1 * inv);
    frow[tid + 512] = __float2bfloat16(a2 * inv);
    if (tid < CHR) frow[HID + tid] = __float2bfloat16(basec[n * CHR + tid]);
}

// ---------------------------------------------------------------------------
// Kernel 2: transpose + convert fp32 [K][N] -> bf16 [N][K]
// ---------------------------------------------------------------------------
__global__ __launch_bounds__(256) void transpose_convert(
    const float* __restrict__ in,   // [K][N]
    bf16*        __restrict__ out,  // [N][K]
    int K, int N)
{
    __shared__ float tile[32][33];
    const int k0 = blockIdx.x * 32;
    const int n0 = blockIdx.y * 32;
    const int tx = threadIdx.x & 31;
    const int ty = threadIdx.x >> 5;      // 0..7

    #pragma unroll
    for (int i = 0; i < 32; i += 8)
        tile[ty + i][tx] = in[(long)(k0 + ty + i) * N + (n0 + tx)];
    __syncthreads();
    #pragma unroll
    for (int i = 0; i < 32; i += 8)
        out[(long)(n0 + ty + i) * K + (k0 + tx)] = __float2bfloat16(tile[tx][ty + i]);
}

// ---------------------------------------------------------------------------
// Kernel 3: bf16 MFMA GEMM, B^T layout:  C[M,N] = act(A[M,K] @ Bt[N,K]^T + bias)
// 64x64 tile, 256 threads = 4 waves in 2x2, wave = 32x32 (2x2 frags 16x16x32).
// BK=32, single LDS buffer, T14 split (load regs early / ds_write late).
// XOR swizzle (row&3)<<4 bytes on LDS 16B chunks to cut ds_read_b128 conflicts.
// OUT_BF16: write bf16 (with relu) else fp32 (with relu).
// ---------------------------------------------------------------------------
template <bool OUT_BF16>
__global__ __launch_bounds__(256) void gemm_bt(
    const bf16*  __restrict__ A,     // [M][K]
    const bf16*  __restrict__ Bt,    // [N][K]
    const float* __restrict__ bias,  // [N]
    void*        __restrict__ Cout,  // [M][N] bf16 or fp32
    int M, int N, int K)
{
    __shared__ short As[64 * 32];    // 64 rows x 32 bf16 (swizzled chunks)
    __shared__ short Bs[64 * 32];

    const int tid  = threadIdx.x;
    const int bm   = blockIdx.x * 64;
    const int bn   = blockIdx.y * 64;
    const int wave = tid >> 6;
    const int lane = tid & 63;
    const int wm   = wave >> 1;      // 0..1
    const int wn   = wave & 1;       // 0..1
    const int g    = lane >> 4;      // k-group 0..3
    const int r    = lane & 15;      // row/col within frag

    // staging assignment: each thread owns one 16B chunk per tile
    const int srow = tid >> 2;       // 0..63
    const int sch  = tid & 3;        // chunk 0..3 (8 bf16 each)
    // swizzled LDS short-index for this thread's chunk
    const int sidx = srow * 32 + ((sch * 8) ^ ((srow & 3) << 3));

    const int nk = K / 32;

    floatx4 acc[2][2];
    #pragma unroll
    for (int i = 0; i < 2; ++i)
        #pragma unroll
        for (int j = 0; j < 2; ++j) acc[i][j] = (floatx4){0.f, 0.f, 0.f, 0.f};

    // prologue: load tile 0 into regs
    short8 areg = *(const short8*)(A  + (long)(bm + srow) * K + sch * 8);
    short8 breg = *(const short8*)(Bt + (long)(bn + srow) * K + sch * 8);
    *(short8*)(&As[sidx]) = areg;
    *(short8*)(&Bs[sidx]) = breg;

    for (int ks = 0; ks < nk; ++ks) {
        __syncthreads();   // staged tile visible

        // T14: issue next tile's global loads before compute
        if (ks + 1 < nk) {
            areg = *(const short8*)(A  + (long)(bm + srow) * K + (ks + 1) * 32 + sch * 8);
            breg = *(const short8*)(Bt + (long)(bn + srow) * K + (ks + 1) * 32 + sch * 8);
        }

        // fragment loads (swizzled) + MFMA
        short8 af[2], bf[2];
        #pragma unroll
        for (int fm = 0; fm < 2; ++fm) {
            const int ar = wm * 32 + fm * 16 + r;
            af[fm] = *(const short8*)(&As[ar * 32 + ((g * 8) ^ ((ar & 3) << 3))]);
        }
        #pragma unroll
        for (int fn = 0; fn < 2; ++fn) {
            const int br = wn * 32 + fn * 16 + r;
            bf[fn] = *(const short8*)(&Bs[br * 32 + ((g * 8) ^ ((br & 3) << 3))]);
        }
        #pragma unroll
        for (int fm = 0; fm < 2; ++fm)
            #pragma unroll
            for (int fn = 0; fn < 2; ++fn)
                acc[fm][fn] = __builtin_amdgcn_mfma_f32_16x16x32_bf16(
                    af[fm], bf[fn], acc[fm][fn], 0, 0, 0);

        __syncthreads();   // all reads done before overwrite

        if (ks + 1 < nk) {
            *(short8*)(&As[sidx]) = areg;
            *(short8*)(&Bs[sidx]) = breg;
        }
    }

    // epilogue: C/D layout col = lane&15, row = (lane>>4)*4 + j
    #pragma unroll
    for (int fm = 0; fm < 2; ++fm) {
        #pragma unroll
        for (int fn = 0; fn < 2; ++fn) {
            const int col = bn + wn * 32 + fn * 16 + r;
            const float bv = bias[col];
            #pragma unroll
            for (int j = 0; j < 4; ++j) {
                const int row = bm + wm * 32 + fm * 16 + g * 4 + j;
                float v = acc[fm][fn][j] + bv;
                v = fmaxf(v, 0.0f);
                if (OUT_BF16)
                    ((bf16*)Cout)[(long)row * N + col] = __float2bfloat16(v);
                else
                    ((float*)Cout)[(long)row * N + col] = v;
            }
        }
    }
}

// ---------------------------------------------------------------------------
// Kernel 4: score[n] = sigmoid(dot(h2[n,:], w3) + b3). One wave per row. fp32.
// ---------------------------------------------------------------------------
__global__ __launch_bounds__(256) void final_kernel(
    const float* __restrict__ h2,  // [N, D2]
    const float* __restrict__ w3,  // [D2]
    const float* __restrict__ b3,  // [1]
    float*       __restrict__ out) // [N]
{
    const int wave = threadIdx.x >> 6;
    const int lane = threadIdx.x & 63;
    const int n = blockIdx.x * 4 + wave;
    if (n >= NSEG) return;

    const float* row = h2 + (long)n * D2;
    float s = 0.f;
    #pragma unroll
    for (int i = 0; i < D2 / 64; ++i)
        s = fmaf(row[lane + i * 64], w3[lane + i * 64], s);

    #pragma unroll
    for (int off = 32; off > 0; off >>= 1)
        s += __shfl_xor(s, off, 64);

    if (lane == 0) {
        float x = s + b3[0];
        out[n] = 1.0f / (1.0f + expf(-x));
    }
}

// ---------------------------------------------------------------------------
extern "C" void kernel_launch(void* const* d_in, const int* in_sizes, int n_in,
                              void* d_out, int out_size, void* d_ws, size_t ws_size,
                              hipStream_t stream) {
    const float* hs    = (const float*)d_in[0];   // [B,S,H]
    const float* basec = (const float*)d_in[1];   // [N,C]
    const float* w1    = (const float*)d_in[2];   // [800,512]
    const float* b1    = (const float*)d_in[3];   // [512]
    const float* w2    = (const float*)d_in[4];   // [512,512]
    const float* b2    = (const float*)d_in[5];   // [512]
    const float* w3    = (const float*)d_in[6];   // [512,1]
    const float* b3    = (const float*)d_in[7];   // [1]
    const int*   tok   = (const int*)d_in[8];     // [T]
    const int*   seg   = (const int*)d_in[9];     // [T]
    float*       out   = (float*)d_out;           // [1,N] -> N floats

    char* ws = (char*)d_ws;
    bf16* feats = (bf16*)ws;  ws += (size_t)NSEG * KF * 2;    // [2048][800] bf16
    bf16* w1t   = (bf16*)ws;  ws += (size_t)D1 * KF * 2;      // [512][800]  bf16
    bf16* w2t   = (bf16*)ws;  ws += (size_t)D2 * D1 * 2;      // [512][512]  bf16
    bf16* h1    = (bf16*)ws;  ws += (size_t)NSEG * D1 * 2;    // [2048][512] bf16
    float* h2   = (float*)ws;                                  // [2048][512] fp32

    pool_kernel<<<NSEG, 256, 0, stream>>>(hs, basec, tok, seg, feats);

    transpose_convert<<<dim3(KF / 32, D1 / 32), 256, 0, stream>>>(w1, w1t, KF, D1);
    transpose_convert<<<dim3(D1 / 32, D2 / 32), 256, 0, stream>>>(w2, w2t, D1, D2);

    gemm_bt<true ><<<dim3(NSEG / 64, D1 / 64), 256, 0, stream>>>(
        feats, w1t, b1, (void*)h1, NSEG, D1, KF);
    gemm_bt<false><<<dim3(NSEG / 64, D2 / 64), 256, 0, stream>>>(
        h1, w2t, b2, (void*)h2, NSEG, D2, D1);

    final_kernel<<<NSEG / 4, 256, 0, stream>>>(h2, w3, b3, out);
}

// Round 6
// 485.759 us; speedup vs baseline: 1.1619x; 1.0090x over previous
//
#include <hip/hip_runtime.h>
#include <hip/hip_bf16.h>
#include <math.h>

// Problem constants
#define HID   768
#define CHR   32
#define NSEG  2048
#define TTOK  16384
#define KF    800           // HID + CHR
#define D1    512
#define D2    512

typedef __hip_bfloat16 bf16;
typedef __attribute__((ext_vector_type(8))) short short8;   // 8 bf16 = 4 VGPR
typedef __attribute__((ext_vector_type(4))) float floatx4;

// ---------------------------------------------------------------------------
// Kernel 1: segment-mean pooling + concat -> bf16 feats. 4-way token ILP.
// Also zero-inits logits[n] (needed before gemm2's atomics).
// ---------------------------------------------------------------------------
__global__ __launch_bounds__(256) void pool_kernel(
    const float* __restrict__ hs,      // [B*S, H]
    const float* __restrict__ basec,   // [N, C]
    const int*   __restrict__ tok,     // [T]
    const int*   __restrict__ seg,     // [T], sorted
    bf16*        __restrict__ feats,   // [N, KF] bf16
    float*       __restrict__ logits)  // [N] zero-init here
{
    const int n   = blockIdx.x;
    const int tid = threadIdx.x;

    int lo;
    {
        int l = 0, r = TTOK;
        while (l < r) { int m = (l + r) >> 1; if (seg[m] < n) l = m + 1; else r = m; }
        lo = l;
    }
    int hi;
    {
        int l = lo, r = TTOK;
        while (l < r) { int m = (l + r) >> 1; if (seg[m] < n + 1) l = m + 1; else r = m; }
        hi = l;
    }

    float a0 = 0.f, a1 = 0.f, a2 = 0.f;
    int t = lo;
    // 4-way ILP: 12 independent loads in flight per iteration
    for (; t + 4 <= hi; t += 4) {
        const float* r0 = hs + (long)tok[t]     * HID;
        const float* r1 = hs + (long)tok[t + 1] * HID;
        const float* r2 = hs + (long)tok[t + 2] * HID;
        const float* r3 = hs + (long)tok[t + 3] * HID;
        float x0a = r0[tid], x0b = r0[tid + 256], x0c = r0[tid + 512];
        float x1a = r1[tid], x1b = r1[tid + 256], x1c = r1[tid + 512];
        float x2a = r2[tid], x2b = r2[tid + 256], x2c = r2[tid + 512];
        float x3a = r3[tid], x3b = r3[tid + 256], x3c = r3[tid + 512];
        a0 += (x0a + x1a) + (x2a + x3a);
        a1 += (x0b + x1b) + (x2b + x3b);
        a2 += (x0c + x1c) + (x2c + x3c);
    }
    for (; t < hi; ++t) {
        const float* row = hs + (long)tok[t] * HID;
        a0 += row[tid];
        a1 += row[tid + 256];
        a2 += row[tid + 512];
    }
    const float inv = 1.0f / (float)((hi - lo) > 0 ? (hi - lo) : 1);
    bf16* frow = feats + (long)n * KF;
    frow[tid]       = __float2bfloat16(a0 * inv);
    frow[tid + 256] = __float2bfloat16(a1 * inv);
    frow[tid + 512] = __float2bfloat16(a2 * inv);
    if (tid < CHR) frow[HID + tid] = __float2bfloat16(basec[n * CHR + tid]);
    if (tid == 0)  logits[n] = 0.0f;
}

// ---------------------------------------------------------------------------
// Kernel 2: both weight transposes (fp32 [K][N] -> bf16 [N][K]) in one launch.
// blockIdx.z selects w1 (z=0, 25x16 tiles) or w2 (z=1, 16x16 tiles).
// ---------------------------------------------------------------------------
__global__ __launch_bounds__(256) void transpose_both(
    const float* __restrict__ w1, bf16* __restrict__ w1t,
    const float* __restrict__ w2, bf16* __restrict__ w2t)
{
    const float* in; bf16* outp; int K, N;
    if (blockIdx.z == 0) { in = w1; outp = w1t; K = KF; N = D1; }
    else {
        if (blockIdx.x >= D1 / 32) return;
        in = w2; outp = w2t; K = D1; N = D2;
    }

    __shared__ float tile[32][33];
    const int k0 = blockIdx.x * 32;
    const int n0 = blockIdx.y * 32;
    const int tx = threadIdx.x & 31;
    const int ty = threadIdx.x >> 5;      // 0..7

    #pragma unroll
    for (int i = 0; i < 32; i += 8)
        tile[ty + i][tx] = in[(long)(k0 + ty + i) * N + (n0 + tx)];
    __syncthreads();
    #pragma unroll
    for (int i = 0; i < 32; i += 8)
        outp[(long)(n0 + ty + i) * K + (k0 + tx)] = __float2bfloat16(tile[tx][ty + i]);
}

// ---------------------------------------------------------------------------
// Kernel 3: bf16 MFMA GEMM, B^T layout: C = relu(A @ Bt^T + bias), bf16 out.
// 64x64 tile, 4 waves 2x2, wave=32x32 (2x2 16x16x32 frags), BK=32,
// reg-staged LDS with XOR chunk swizzle, T14 issue-early/write-late.
// ---------------------------------------------------------------------------
__global__ __launch_bounds__(256) void gemm_bt_relu(
    const bf16*  __restrict__ A,     // [M][K]
    const bf16*  __restrict__ Bt,    // [N][K]
    const float* __restrict__ bias,  // [N]
    bf16*        __restrict__ Cout,  // [M][N]
    int M, int N, int K)
{
    __shared__ short As[64 * 32];
    __shared__ short Bs[64 * 32];

    const int tid  = threadIdx.x;
    const int bm   = blockIdx.x * 64;
    const int bn   = blockIdx.y * 64;
    const int wave = tid >> 6;
    const int lane = tid & 63;
    const int wm   = wave >> 1;
    const int wn   = wave & 1;
    const int g    = lane >> 4;
    const int r    = lane & 15;

    const int srow = tid >> 2;
    const int sch  = tid & 3;
    const int sidx = srow * 32 + ((sch * 8) ^ ((srow & 3) << 3));

    const int nk = K / 32;

    floatx4 acc[2][2];
    #pragma unroll
    for (int i = 0; i < 2; ++i)
        #pragma unroll
        for (int j = 0; j < 2; ++j) acc[i][j] = (floatx4){0.f, 0.f, 0.f, 0.f};

    short8 areg = *(const short8*)(A  + (long)(bm + srow) * K + sch * 8);
    short8 breg = *(const short8*)(Bt + (long)(bn + srow) * K + sch * 8);
    *(short8*)(&As[sidx]) = areg;
    *(short8*)(&Bs[sidx]) = breg;

    for (int ks = 0; ks < nk; ++ks) {
        __syncthreads();

        if (ks + 1 < nk) {
            areg = *(const short8*)(A  + (long)(bm + srow) * K + (ks + 1) * 32 + sch * 8);
            breg = *(const short8*)(Bt + (long)(bn + srow) * K + (ks + 1) * 32 + sch * 8);
        }

        short8 af[2], bfr[2];
        #pragma unroll
        for (int fm = 0; fm < 2; ++fm) {
            const int ar = wm * 32 + fm * 16 + r;
            af[fm] = *(const short8*)(&As[ar * 32 + ((g * 8) ^ ((ar & 3) << 3))]);
        }
        #pragma unroll
        for (int fn = 0; fn < 2; ++fn) {
            const int br = wn * 32 + fn * 16 + r;
            bfr[fn] = *(const short8*)(&Bs[br * 32 + ((g * 8) ^ ((br & 3) << 3))]);
        }
        #pragma unroll
        for (int fm = 0; fm < 2; ++fm)
            #pragma unroll
            for (int fn = 0; fn < 2; ++fn)
                acc[fm][fn] = __builtin_amdgcn_mfma_f32_16x16x32_bf16(
                    af[fm], bfr[fn], acc[fm][fn], 0, 0, 0);

        __syncthreads();

        if (ks + 1 < nk) {
            *(short8*)(&As[sidx]) = areg;
            *(short8*)(&Bs[sidx]) = breg;
        }
    }

    #pragma unroll
    for (int fm = 0; fm < 2; ++fm) {
        #pragma unroll
        for (int fn = 0; fn < 2; ++fn) {
            const int col = bn + wn * 32 + fn * 16 + r;
            const float bv = bias[col];
            #pragma unroll
            for (int j = 0; j < 4; ++j) {
                const int row = bm + wm * 32 + fm * 16 + g * 4 + j;
                float v = fmaxf(acc[fm][fn][j] + bv, 0.0f);
                Cout[(long)row * N + col] = __float2bfloat16(v);
            }
        }
    }
}

// ---------------------------------------------------------------------------
// Kernel 4: GEMM2 fused with final dot: per-block partial of
// relu(A@Bt^T + bias) . w3, atomicAdd'ed into logits[row].
// ---------------------------------------------------------------------------
__global__ __launch_bounds__(256) void gemm_bt_dot(
    const bf16*  __restrict__ A,      // [M][K]
    const bf16*  __restrict__ Bt,     // [N][K]
    const float* __restrict__ bias,   // [N]
    const float* __restrict__ w3,     // [N]
    float*       __restrict__ logits, // [M], pre-zeroed
    int M, int N, int K)
{
    __shared__ short As[64 * 32];
    __shared__ short Bs[64 * 32];

    const int tid  = threadIdx.x;
    const int bm   = blockIdx.x * 64;
    const int bn   = blockIdx.y * 64;
    const int wave = tid >> 6;
    const int lane = tid & 63;
    const int wm   = wave >> 1;
    const int wn   = wave & 1;
    const int g    = lane >> 4;
    const int r    = lane & 15;

    const int srow = tid >> 2;
    const int sch  = tid & 3;
    const int sidx = srow * 32 + ((sch * 8) ^ ((srow & 3) << 3));

    const int nk = K / 32;

    floatx4 acc[2][2];
    #pragma unroll
    for (int i = 0; i < 2; ++i)
        #pragma unroll
        for (int j = 0; j < 2; ++j) acc[i][j] = (floatx4){0.f, 0.f, 0.f, 0.f};

    short8 areg = *(const short8*)(A  + (long)(bm + srow) * K + sch * 8);
    short8 breg = *(const short8*)(Bt + (long)(bn + srow) * K + sch * 8);
    *(short8*)(&As[sidx]) = areg;
    *(short8*)(&Bs[sidx]) = breg;

    for (int ks = 0; ks < nk; ++ks) {
        __syncthreads();

        if (ks + 1 < nk) {
            areg = *(const short8*)(A  + (long)(bm + srow) * K + (ks + 1) * 32 + sch * 8);
            breg = *(const short8*)(Bt + (long)(bn + srow) * K + (ks + 1) * 32 + sch * 8);
        }

        short8 af[2], bfr[2];
        #pragma unroll
        for (int fm = 0; fm < 2; ++fm) {
            const int ar = wm * 32 + fm * 16 + r;
            af[fm] = *(const short8*)(&As[ar * 32 + ((g * 8) ^ ((ar & 3) << 3))]);
        }
        #pragma unroll
        for (int fn = 0; fn < 2; ++fn) {
            const int br = wn * 32 + fn * 16 + r;
            bfr[fn] = *(const short8*)(&Bs[br * 32 + ((g * 8) ^ ((br & 3) << 3))]);
        }
        #pragma unroll
        for (int fm = 0; fm < 2; ++fm)
            #pragma unroll
            for (int fn = 0; fn < 2; ++fn)
                acc[fm][fn] = __builtin_amdgcn_mfma_f32_16x16x32_bf16(
                    af[fm], bfr[fn], acc[fm][fn], 0, 0, 0);

        __syncthreads();

        if (ks + 1 < nk) {
            *(short8*)(&As[sidx]) = areg;
            *(short8*)(&Bs[sidx]) = breg;
        }
    }

    // epilogue: v = relu(acc + bias[col]) * w3[col]; reduce over col slice;
    // one atomicAdd per (row) from lane r==0 of each 16-lane group.
    #pragma unroll
    for (int fm = 0; fm < 2; ++fm) {
        #pragma unroll
        for (int j = 0; j < 4; ++j) {
            float s = 0.f;
            #pragma unroll
            for (int fn = 0; fn < 2; ++fn) {
                const int col = bn + wn * 32 + fn * 16 + r;
                float v = fmaxf(acc[fm][fn][j] + bias[col], 0.0f);
                s = fmaf(v, w3[col], s);
            }
            s += __shfl_xor(s, 1, 64);
            s += __shfl_xor(s, 2, 64);
            s += __shfl_xor(s, 4, 64);
            s += __shfl_xor(s, 8, 64);
            if (r == 0) {
                const int row = bm + wm * 32 + fm * 16 + g * 4 + j;
                atomicAdd(&logits[row], s);
            }
        }
    }
}

// ---------------------------------------------------------------------------
// Kernel 5: out[n] = sigmoid(logits[n] + b3)
// ---------------------------------------------------------------------------
__global__ __launch_bounds__(256) void sigmoid_kernel(
    const float* __restrict__ logits,
    const float* __restrict__ b3,
    float*       __restrict__ out)
{
    const int n = blockIdx.x * 256 + threadIdx.x;
    if (n < NSEG) {
        float x = logits[n] + b3[0];
        out[n] = 1.0f / (1.0f + expf(-x));
    }
}

// ---------------------------------------------------------------------------
extern "C" void kernel_launch(void* const* d_in, const int* in_sizes, int n_in,
                              void* d_out, int out_size, void* d_ws, size_t ws_size,
                              hipStream_t stream) {
    const float* hs    = (const float*)d_in[0];
    const float* basec = (const float*)d_in[1];
    const float* w1    = (const float*)d_in[2];
    const float* b1    = (const float*)d_in[3];
    const float* w2    = (const float*)d_in[4];
    const float* b2    = (const float*)d_in[5];
    const float* w3    = (const float*)d_in[6];
    const float* b3    = (const float*)d_in[7];
    const int*   tok   = (const int*)d_in[8];
    const int*   seg   = (const int*)d_in[9];
    float*       out   = (float*)d_out;

    char* ws = (char*)d_ws;
    bf16*  feats  = (bf16*)ws;   ws += (size_t)NSEG * KF * 2;
    bf16*  w1t    = (bf16*)ws;   ws += (size_t)D1 * KF * 2;
    bf16*  w2t    = (bf16*)ws;   ws += (size_t)D2 * D1 * 2;
    bf16*  h1     = (bf16*)ws;   ws += (size_t)NSEG * D1 * 2;
    float* logits = (float*)ws;

    pool_kernel<<<NSEG, 256, 0, stream>>>(hs, basec, tok, seg, feats, logits);

    transpose_both<<<dim3(KF / 32, D1 / 32, 2), 256, 0, stream>>>(w1, w1t, w2, w2t);

    gemm_bt_relu<<<dim3(NSEG / 64, D1 / 64), 256, 0, stream>>>(
        feats, w1t, b1, h1, NSEG, D1, KF);

    gemm_bt_dot<<<dim3(NSEG / 64, D2 / 64), 256, 0, stream>>>(
        h1, w2t, b2, w3, logits, NSEG, D2, D1);

    sigmoid_kernel<<<NSEG / 256, 256, 0, stream>>>(logits, b3, out);
}